// Round 4
// baseline (116.903 us; speedup 1.0000x reference)
//
#include <hip/hip_runtime.h>

// GR4J production-store scan, parallelized by contraction.
//
// Round-12: one map per thread (TPB=384), single-buffered LDS scan reads.
// r11 post-mortem: total unchanged (111us); top-5 now the harness's 268MB
// workspace re-poison fill (~45us, timed) => floor = fill + normalize(~14) +
// overhead ~ 60-65us. scan_hexa fell below 44us but not to the ~15us the op
// budget predicts. Diagnosis: phase-1 critical path was 2 serial ~1500-inst
// builds on waves 0-1 only (hasB threads), holding 64 VGPRs of prefetched
// wb across the first build; all other waves wait at the barrier.
//   - TPB=384 (6 waves): NMAP=352<=384 => every thread builds EXACTLY ONE
//     map. Build critical path halved; no cross-build prefetch registers.
//   - still 2 blocks/CU (LDS 77.6KB): 12 waves/CU = 3 waves/SIMD in build.
//   - phase 2a/2b single-buffered (A/B read then eval per stage): -64 VGPR;
//     per-stage LDS round-trip (~120cyc x 16 stages) hidden by co-resident
//     waves at 3/SIMD.
//   - __launch_bounds__(384,3); numerics IDENTICAL to r11 (absmax-safe).
// Fallback to the round-1 kernel for odd shapes.

typedef float f32x4 __attribute__((ext_vector_type(4)));

#define LCH      32            // main steps per chunk
#define CPB      128           // chunks per block
#define TPB      384           // threads per block (6 waves)
#define BSTEPS   4096          // LCH*CPB main steps per block
#define WUP      1536          // warm-up steps
#define WUMAP    96            // WUP/16 maps per chunk window
#define WSTO     12            // WUMAP/8 warm stages
#define NMAP     352           // map window union = 2*(CPB-1)+WUMAP (+pad even)
#define HODD     176           // odd-map slot offset = NMAP/2
#define NCK      129           // main k tile padded cols (32 rows; 128 used)
#define NMST     4             // main stages = LCH/8
#define NWAVE    6             // TPB/64

// Chebyshev node values cos((2j+1)pi/16) and DCT constants
#define CC1 0.98078528f
#define CC2 0.92387953f
#define CC3 0.83146961f
#define CC4 0.70710678f
#define CC5 0.55557023f
#define CC6 0.38268343f
#define CC7 0.19509032f

// one exact cubic+quintic step, warm-up flavor (state only)
__device__ __forceinline__ void stepk(float& s, const f32x4 k, float gma) {
    float s2m = s * s;
    float t1  = fmaf(k.y, s, k.x);
    float t2  = fmaf(k.w, s, k.z);
    float s1  = fmaf(s2m, t2, t1);
    float w2  = s1 * s1;
    float q4  = gma * s1;
    float w4  = w2 * w2;
    s = fmaf(-q4, w4, s1);
}

// main flavor: also emit ps (= relu(s1 - s_prev), exact) and pc (= gma*s1^5)
__device__ __forceinline__ void stepk_m(float& s, const f32x4 k, float gma,
                                        float& ps_o, float& pc_o) {
    float sp  = s;
    float s2m = s * s;
    float t1  = fmaf(k.y, s, k.x);
    float t2  = fmaf(k.w, s, k.z);
    float s1  = fmaf(s2m, t2, t1);
    float w2  = s1 * s1;
    float q4  = gma * s1;
    float w4  = w2 * w2;
    s = fmaf(-q4, w4, s1);
    ps_o = fmaxf(s1 - sp, 0.0f);
    pc_o = q4 * w4;
}

struct KC { float inv, x1, x1sq, x1_2, two_x1cu, five_x1sq, four_x1; };

// per-step cubic coefficients (identical numerics to round-8 phase 1)
// note: P=E=0 yields exactly (0,1,0,0) => zero-padding needs no special case.
__device__ __forceinline__ f32x4 mkk(float P, float Ev, const KC c,
                                     float& pn_o, float& en_o) {
    float d  = P - Ev;
    float pn = fmaxf(d, 0.f), en = fmaxf(-d, 0.f);
    float up = pn * c.inv, un = en * c.inv;
    float tp = up * fmaf(up * up, -(1.f/3.f), 1.f);
    float tn = un * fmaf(un * un, -(1.f/3.f), 1.f);
    float al = tp * c.inv, be = tn * c.inv;
    float a2 = al * al,  a3v = a2 * al;
    float b2 = be * be,  b3v = b2 * be;
    float e2 = fmaf(-be, c.x1, 1.f);
    float k0 = tp * c.x1;
    float k1 = 1.f - a2 * c.x1sq - (c.x1_2 * be * e2 + c.two_x1cu * b3v);
    float k2 = (a3v * c.x1sq - al) - (c.x1_2 * b2 - be * e2 - c.five_x1sq * b3v);
    float k3 = a2 + b2 - c.four_x1 * b3v;
    pn_o = pn; en_o = en;
    return (f32x4){k0, k1, k2, k3};
}

__global__ __launch_bounds__(TPB, 3) void scan_h384(
        const float* __restrict__ x, const float* __restrict__ x1p,
        f32x4* __restrict__ pspc4, f32x4* __restrict__ s4,
        float* __restrict__ partials) {
    __shared__ f32x4 tk[32 * NCK];              // 66048 B main k-tile
    __shared__ f32x4 mapA[NMAP];                // 5632 B  map coeffs d0..d3
    __shared__ f32x4 mapB[NMAP];                // 5632 B  map coeffs d4..d7
    __shared__ float red[8 * NWAVE];            // total ~77.6 KB -> 2 blk/CU

    const int tid  = threadIdx.x;
    const int lane = tid & 63;
    const int wid  = tid >> 6;
    const int b    = blockIdx.x;

    const float x1 = x1p[0];
    KC c;
    c.inv = 1.0f / x1; c.x1 = x1; c.x1sq = x1 * x1; c.x1_2 = 2.0f * x1;
    c.two_x1cu = 2.0f * x1 * c.x1sq; c.five_x1sq = 5.0f * c.x1sq;
    c.four_x1 = 4.0f * x1;
    const float gma = 64.0f / (6561.0f * c.x1sq * c.x1sq);   // perc = gma*s1^5
    const float cen = (184.0f / 350.0f) * x1;   // sigma domain center
    const float hw  = (208.0f / 350.0f) * x1;   // sigma domain half-width
    const float ihw = 1.0f / hw;

    float spn = 0.f, sen = 0.f, qpn = 0.f, qen = 0.f;

    // ---- phase 1 (ONE map per thread): build degree-7 16-step maps directly
    //      from x; main-region maps also deposit their exact per-step cubics
    //      into tk and accumulate pn/en stats. ----
    if (tid < NMAP) {
        const f32x4* __restrict__ x4 = (const f32x4*)x;  // one f32x4 == 2 steps
        const f32x4 z4 = (f32x4){0.f, 0.f, 0.f, 0.f};
        const long gp = (long)b * (BSTEPS / 2) + 8L * (tid - WUMAP);
        f32x4 w[8];
        #pragma unroll
        for (int q = 0; q < 8; ++q) {
            const long g = gp + q;
            w[q] = (g >= 0) ? x4[g] : z4;
        }

        float snode[8];
        {
            const float ND[8] = { CC1,  CC3,  CC5,  CC7, -CC7, -CC5, -CC3, -CC1};
            #pragma unroll
            for (int j = 0; j < 8; ++j) snode[j] = fmaf(hw, ND[j], cen);
        }

        const int m = tid - WUMAP;               // map index in [-96, 256)
        const bool mainm = (m >= 0);
        float sv[8];
        #pragma unroll
        for (int j = 0; j < 8; ++j) sv[j] = snode[j];
        #pragma unroll
        for (int q = 0; q < 8; ++q) {            // 8 pairs = 16 steps
            float pn0, en0, pn1, en1;
            const f32x4 kA = mkk(w[q].x, w[q].y, c, pn0, en0);
            const f32x4 kB = mkk(w[q].z, w[q].w, c, pn1, en1);
            #pragma unroll
            for (int j = 0; j < 8; ++j) {        // 8 independent node chains
                stepk(sv[j], kA, gma);
                stepk(sv[j], kB, gma);
            }
            if (mainm) {
                spn += pn0 + pn1; sen += en0 + en1;
                qpn = fmaf(pn0, pn0, fmaf(pn1, pn1, qpn));
                qen = fmaf(en0, en0, fmaf(en1, en1, qen));
                const int t = 16 * m + 2 * q;                // block-local step
                const int r = t & 31, col = t >> 5;
                tk[r * NCK + col]       = kA;
                tk[(r + 1) * NCK + col] = kB;
            }
        }
        float v[8];
        #pragma unroll
        for (int j = 0; j < 8; ++j) v[j] = (sv[j] - cen) * ihw;
        const float e0 = v[0] + v[7], e1 = v[1] + v[6];
        const float e2 = v[2] + v[5], e3 = v[3] + v[4];
        const float o0 = v[0] - v[7], o1 = v[1] - v[6];
        const float o2 = v[2] - v[5], o3 = v[3] - v[4];
        const float a0 = 0.125f * (e0 + e1 + e2 + e3);
        const float a1 = 0.25f * (o0*CC1 + o1*CC3 + o2*CC5 + o3*CC7);
        const float a2 = 0.25f * ((e0 - e3)*CC2 + (e1 - e2)*CC6);
        const float a3 = 0.25f * (o0*CC3 - o1*CC7 - o2*CC1 - o3*CC5);
        const float a4 = 0.25f * CC4 * ((e0 + e3) - (e1 + e2));
        const float a5 = 0.25f * (o0*CC5 - o1*CC1 + o2*CC7 + o3*CC3);
        const float a6 = 0.25f * ((e0 - e3)*CC6 - (e1 - e2)*CC2);
        const float a7 = 0.25f * (o0*CC7 - o1*CC5 + o2*CC3 - o3*CC1);
        const int slot = (tid >> 1) + ((tid & 1) ? HODD : 0);
        mapA[slot] = (f32x4){a0 - a2 + a4 - a6,
                             a1 - 3.0f*a3 + 5.0f*a5 - 7.0f*a7,
                             2.0f*a2 - 8.0f*a4 + 18.0f*a6,
                             4.0f*a3 - 20.0f*a5 + 56.0f*a7};
        mapB[slot] = (f32x4){8.0f*a4 - 48.0f*a6,
                             16.0f*a5 - 112.0f*a7,
                             32.0f*a6,
                             64.0f*a7};
    }
    __syncthreads();

    // ---- phase 2a: warm-up sigma-scan, 3 dep levels per 16-step map ----
    float aps = 0.f, apc = 0.f, qps = 0.f, qpc = 0.f;
    float sg = 0.f;
    if (tid < CPB) {
        const int l = tid;
        const long gstart = ((long)b * CPB + l) * LCH;
        const float s0 = (gstart >= WUP) ? 0.47f * x1 : 0.0f;  // attractor / exact-0
        sg = (s0 - cen) * ihw;
        f32x4 A[8], B[8];
        #pragma unroll 1
        for (int st = 0; st < WSTO; ++st) {
            const int base = l + 4 * st;         // map m = 2l+8st+u (slot-split)
            #pragma unroll
            for (int u = 0; u < 8; ++u)
                A[u] = mapA[base + (u >> 1) + ((u & 1) ? HODD : 0)];
            #pragma unroll
            for (int u = 0; u < 8; ++u)
                B[u] = mapB[base + (u >> 1) + ((u & 1) ? HODD : 0)];
            #pragma unroll
            for (int u = 0; u < 8; ++u) {        // Estrin deg-7: 3 levels
                const float s2  = sg * sg;
                const float p0  = fmaf(A[u].y, sg, A[u].x);
                const float p1  = fmaf(A[u].w, sg, A[u].z);
                const float p2  = fmaf(B[u].y, sg, B[u].x);
                const float p3  = fmaf(B[u].w, sg, B[u].z);
                const float s4v = s2 * s2;
                const float q0  = fmaf(p1, s2, p0);
                const float q1  = fmaf(p3, s2, p2);
                sg = fmaf(q1, s4v, q0);
            }
        }
    }
    const float s_after = fmaf(hw, sg, cen);

    // ---- phase 2b: exact main scan with outputs (lanes < 128) ----
    if (tid < CPB) {
        const int l = tid;
        const size_t chunk = (size_t)b * CPB + l;
        float s = s_after;
        f32x4 K[8];
        #pragma unroll 1
        for (int m = 0; m < NMST; ++m) {
            const int base = (m << 3) * NCK + l;
            #pragma unroll
            for (int u = 0; u < 8; ++u) K[u] = tk[base + u * NCK];
            float psv[8], pcv[8], sv[8];
            #pragma unroll
            for (int u = 0; u < 8; ++u) {
                stepk_m(s, K[u], gma, psv[u], pcv[u]);
                sv[u] = s;
            }
            #pragma unroll
            for (int u = 0; u < 8; ++u) {
                aps += psv[u]; apc += pcv[u];
                qps = fmaf(psv[u], psv[u], qps); qpc = fmaf(pcv[u], pcv[u], qpc);
            }
            const size_t pb = chunk * 16 + 4 * m;
            pspc4[pb + 0] = (f32x4){psv[0], pcv[0], psv[1], pcv[1]};
            pspc4[pb + 1] = (f32x4){psv[2], pcv[2], psv[3], pcv[3]};
            pspc4[pb + 2] = (f32x4){psv[4], pcv[4], psv[5], pcv[5]};
            pspc4[pb + 3] = (f32x4){psv[6], pcv[6], psv[7], pcv[7]};
            const size_t sb = chunk * 8 + 2 * m;
            s4[sb]     = (f32x4){sv[0], sv[1], sv[2], sv[3]};
            s4[sb + 1] = (f32x4){sv[4], sv[5], sv[6], sv[7]};
        }
    }

    // ---- block reduction of 8 stat accumulators ----
    float vals[8] = {spn, sen, aps, apc, qpn, qen, qps, qpc};
    #pragma unroll
    for (int k = 0; k < 8; ++k) {
        float v = vals[k];
        #pragma unroll
        for (int off = 32; off > 0; off >>= 1) v += __shfl_down(v, off, 64);
        if (lane == 0) red[k * NWAVE + wid] = v;
    }
    __syncthreads();
    if (tid < 8) {
        float v = 0.f;
        #pragma unroll
        for (int wv = 0; wv < NWAVE; ++wv) v += red[tid * NWAVE + wv];
        partials[b * 8 + tid] = v;
    }
}

// ---- stats finalize folded in + fused normalize/assemble (unchanged) ----
__global__ __launch_bounds__(256) void normalize_stats(
        const float* __restrict__ x, const f32x4* __restrict__ pspc4,
        const float* __restrict__ pA, f32x4* __restrict__ out4,
        int nA, int Thalf, int T) {
    __shared__ float red[256];
    __shared__ float sst[8];
    const int tid = threadIdx.x;
    {   // components: 0 pn,1 en,2 ps,3 pc (sums); 4..7 squares
        const int c = tid & 7;
        float v = 0.f;
        for (int i = tid >> 3; i < nA; i += 32) v += pA[i * 8 + c];
        red[tid] = v;
        __syncthreads();
        for (int off = 128; off >= 8; off >>= 1) {
            if (tid < off) red[tid] += red[tid + off];
            __syncthreads();
        }
        if (tid == 0) {
            const float invT = 1.0f / (float)T;
            #pragma unroll
            for (int k = 0; k < 4; ++k) {
                float mu  = red[k] * invT;
                float var = fmaxf(fmaf(-mu, mu, red[4 + k] * invT), 0.0f);
                sst[k]     = mu;
                sst[4 + k] = (var > 0.0f) ? rsqrtf(var) : 0.0f;
            }
        }
        __syncthreads();
    }
    const float mu0 = sst[0], mu1 = sst[1], mu2 = sst[2], mu3 = sst[3];
    const float is0 = sst[4], is1 = sst[5], is2 = sst[6], is3 = sst[7];
    const f32x4* __restrict__ x4 = (const f32x4*)x;
    for (int i = blockIdx.x * 256 + tid; i < Thalf; i += 1024 * 256) {
        f32x4 xv = x4[i];
        f32x4 pq = pspc4[i];
        float d0 = xv.x - xv.y, d1 = xv.z - xv.w;
        out4[2 * i]     = (f32x4){(fmaxf(d0, 0.f) - mu0) * is0,
                                  (fmaxf(-d0, 0.f) - mu1) * is1,
                                  (pq.x - mu2) * is2,
                                  (pq.y - mu3) * is3};
        out4[2 * i + 1] = (f32x4){(fmaxf(d1, 0.f) - mu0) * is0,
                                  (fmaxf(-d1, 0.f) - mu1) * is1,
                                  (pq.z - mu2) * is2,
                                  (pq.w - mu3) * is3};
    }
}

// ---------------- round-1 fallback (proven; own WARMUP=2048, s0=0) ----------
#define L_CHUNK  128
#define FB_WARMUP 2048
__device__ __forceinline__ float inv1p_fb(float a) {
    float i1 = 1.0f - a;
    float i2 = fmaf(-a, i1, 1.0f);
    return fmaf(-a, i2, 1.0f);
}
struct SCfb { float x1, inv_x1, c49; };
__device__ __forceinline__ void scan_step_fb(float& s, float P, float E, const SCfb c,
                                             float& pn, float& en, float& ps, float& pc) {
    float d = P - E;
    float pn_ = fmaxf(d, 0.0f), en_ = fmaxf(-d, 0.0f);
    float up = pn_ * c.inv_x1;
    float tp = up * fmaf(up * up, -(1.0f / 3.0f), 1.0f);
    float un = en_ * c.inv_x1;
    float tn = un * fmaf(un * un, -(1.0f / 3.0f), 1.0f);
    float r = s * c.inv_x1;
    float ps_ = (tp * c.x1) * fmaf(-r, r, 1.0f) * inv1p_fb(r * tp);
    float es_ = (s * (2.0f - r)) * tn * inv1p_fb((1.0f - r) * tn);
    float s1 = s + ps_ - es_;
    float z = s1 * c.c49, z2 = z * z, v = z2 * z2;
    float t = fmaf(v, fmaf(v, 0.15625f, -0.25f), 1.0f);
    float s2 = s1 * t;
    pn = pn_; en = en_; ps = ps_; pc = s1 - s2; s = s2;
}
__global__ __launch_bounds__(256) void scan_kernel_fb(
        const float* __restrict__ x, const float* __restrict__ x1ptr,
        float* __restrict__ out, float* __restrict__ s_store,
        float* __restrict__ partials, int T) {
    const int c = blockIdx.x * blockDim.x + threadIdx.x;
    const int nchunks = (T + L_CHUNK - 1) / L_CHUNK;
    SCfb cc; cc.x1 = x1ptr[0]; cc.inv_x1 = 1.0f / cc.x1; cc.c49 = (4.0f / 9.0f) * cc.inv_x1;
    float s1a[4] = {0.f, 0.f, 0.f, 0.f};
    float s2a[4] = {0.f, 0.f, 0.f, 0.f};
    if (c < nchunks) {
        const int g0 = c * L_CHUNK;
        const int g1 = min(g0 + L_CHUNK, T);
        const int w0 = max(g0 - FB_WARMUP, 0);
        float s = 0.0f; float pn, en, ps, pc;
        const float2* __restrict__ x2 = (const float2*)x;
        for (int t = w0; t < g0; ++t) { float2 xv = x2[t]; scan_step_fb(s, xv.x, xv.y, cc, pn, en, ps, pc); }
        float4* __restrict__ out4 = (float4*)out;
        for (int t = g0; t < g1; ++t) {
            float2 xv = x2[t];
            scan_step_fb(s, xv.x, xv.y, cc, pn, en, ps, pc);
            out4[t] = make_float4(pn, en, ps, pc);
            s_store[t] = s;
            s1a[0] += pn; s1a[1] += en; s1a[2] += ps; s1a[3] += pc;
            s2a[0] = fmaf(pn, pn, s2a[0]); s2a[1] = fmaf(en, en, s2a[1]);
            s2a[2] = fmaf(ps, ps, s2a[2]); s2a[3] = fmaf(pc, pc, s2a[3]);
        }
    }
    __shared__ float red[256];
    float vals[8] = {s1a[0], s1a[1], s1a[2], s1a[3], s2a[0], s2a[1], s2a[2], s2a[3]};
    for (int k = 0; k < 8; ++k) {
        red[threadIdx.x] = vals[k];
        __syncthreads();
        for (int off = 128; off > 0; off >>= 1) {
            if ((int)threadIdx.x < off) red[threadIdx.x] += red[threadIdx.x + off];
            __syncthreads();
        }
        if (threadIdx.x == 0) partials[blockIdx.x * 8 + k] = red[0];
        __syncthreads();
    }
}
__global__ __launch_bounds__(64) void finalize_fb(
        const float* __restrict__ partials, float* __restrict__ stats, int nblk, int T) {
    const int lane = threadIdx.x;
    float v[8] = {0.f, 0.f, 0.f, 0.f, 0.f, 0.f, 0.f, 0.f};
    for (int b = lane; b < nblk; b += 64)
        for (int k = 0; k < 8; ++k) v[k] += partials[b * 8 + k];
    #pragma unroll
    for (int k = 0; k < 8; ++k)
        for (int off = 32; off > 0; off >>= 1) v[k] += __shfl_down(v[k], off, 64);
    if (lane == 0) {
        const float invT = 1.0f / (float)T;
        for (int k = 0; k < 4; ++k) {
            float mu = v[k] * invT;
            float var = fmaxf(fmaf(-mu, mu, v[k + 4] * invT), 0.0f);
            stats[k] = mu;
            stats[4 + k] = (var > 0.0f) ? rsqrtf(var) : 0.0f;
        }
    }
}
__global__ __launch_bounds__(256) void normalize_fb(
        float* __restrict__ out, const float* __restrict__ stats, int T) {
    const int t = blockIdx.x * blockDim.x + threadIdx.x;
    if (t >= T) return;
    const float4 mu = *(const float4*)stats;
    const float4 is = *(const float4*)(stats + 4);
    float4* o4 = (float4*)out;
    float4 v = o4[t];
    v.x = (v.x - mu.x) * is.x; v.y = (v.y - mu.y) * is.y;
    v.z = (v.z - mu.z) * is.z; v.w = (v.w - mu.w) * is.w;
    o4[t] = v;
}
// -----------------------------------------------------------------------------

extern "C" void kernel_launch(void* const* d_in, const int* in_sizes, int n_in,
                              void* d_out, int out_size, void* d_ws, size_t ws_size,
                              hipStream_t stream) {
    const float* x  = (const float*)d_in[0];
    const float* x1 = (const float*)d_in[1];
    const int T = in_sizes[0] / 2;

    float* out     = (float*)d_out;                // (T,4)
    float* s_store = out + 4 * (size_t)T;          // (T,)

    const int nblk = T / BSTEPS;                   // scan blocks (fast path)

    float* pA = (float*)d_ws;                      // nblk*8 floats (<=4096)
    const size_t pq_off = 4608;                    // f32x4-aligned float offset
    const size_t need = (pq_off + 2 * (size_t)T) * sizeof(float);

    const bool fast = (T % BSTEPS == 0) && nblk >= 1 && nblk <= 512 &&
                      (ws_size >= need);

    if (fast) {
        f32x4* pspc4 = (f32x4*)((float*)d_ws + pq_off);
        scan_h384<<<nblk, TPB, 0, stream>>>(x, x1, pspc4, (f32x4*)s_store, pA);
        normalize_stats<<<1024, 256, 0, stream>>>(x, pspc4, pA,
                                                  (f32x4*)out, nblk, T / 2, T);
    } else {
        float* stats    = (float*)d_ws;
        float* partials = stats + 8;
        const int nchunks = (T + L_CHUNK - 1) / L_CHUNK;
        const int nblkA = (nchunks + 255) / 256;
        scan_kernel_fb<<<nblkA, 256, 0, stream>>>(x, x1, out, s_store, partials, T);
        finalize_fb<<<1, 64, 0, stream>>>(partials, stats, nblkA, T);
        normalize_fb<<<(T + 255) / 256, 256, 0, stream>>>(out, stats, T);
    }
}

// Round 5
// 116.295 us; speedup vs baseline: 1.0052x; 1.0052x over previous
//
#include <hip/hip_runtime.h>

// GR4J production-store scan, parallelized by contraction.
//
// Round-13: occupancy fix — TPB=512, VGPR<=128 (launch_bounds(512,4)),
// half k-tile + cheap restage => 16 waves/CU (was 12, VGPR-capped at 132).
// r12 post-mortem: waves/SIMD = floor(512/VGPR) = 3 at VGPR=132 — every
// structural change so far left resident parallelism unchanged; VALUBusy
// ~26% is occupancy starvation (~11us of VALU work inflated to ~40us wall).
//   - TPB=512 (8 waves), BSTEPS=4096, CPB=128, LCH=32, 16-step maps
//     (PROVEN width/numerics — zero new accuracy risk). One map/thread.
//   - LDS 44.5KB: k-tile halved to 16 rows (steps 0..15 of each chunk,
//     deposited by even main maps); steps 16..31 re-staged by all 512
//     threads (2 pairs each, ~70 VALU) into the same tile after 2b-h1.
//   - __launch_bounds__(512,4) => compiler must fit 4 waves/EU => VGPR<=128.
//   - stats: even-map steps in build, odd-map steps in restage (exact
//     partition of the 4096 main steps; warm maps contribute none).
// Fallback to the round-1 kernel for odd shapes.

typedef float f32x4 __attribute__((ext_vector_type(4)));

#define LCH      32            // main steps per chunk
#define CPB      128           // chunks per block
#define TPB      512           // threads per block (8 waves)
#define BSTEPS   4096          // LCH*CPB main steps per block
#define WUP      1536          // warm-up steps
#define WUMAP    96            // WUP/16 warm maps per chunk window
#define WSTO     12            // WUMAP/8 warm stages
#define NMAP     352           // map window union = 2*(CPB-1)+WUMAP (+pad even)
#define HODD     176           // odd-map slot offset = NMAP/2
#define NCK      129           // k-tile padded cols (16 rows; 128 used)
#define NWAVE    8             // TPB/64

// Chebyshev node values cos((2j+1)pi/16) and DCT constants
#define CC1 0.98078528f
#define CC2 0.92387953f
#define CC3 0.83146961f
#define CC4 0.70710678f
#define CC5 0.55557023f
#define CC6 0.38268343f
#define CC7 0.19509032f

// one exact cubic+quintic step, warm-up flavor (state only)
__device__ __forceinline__ void stepk(float& s, const f32x4 k, float gma) {
    float s2m = s * s;
    float t1  = fmaf(k.y, s, k.x);
    float t2  = fmaf(k.w, s, k.z);
    float s1  = fmaf(s2m, t2, t1);
    float w2  = s1 * s1;
    float q4  = gma * s1;
    float w4  = w2 * w2;
    s = fmaf(-q4, w4, s1);
}

// main flavor: also emit ps (= relu(s1 - s_prev), exact) and pc (= gma*s1^5)
__device__ __forceinline__ void stepk_m(float& s, const f32x4 k, float gma,
                                        float& ps_o, float& pc_o) {
    float sp  = s;
    float s2m = s * s;
    float t1  = fmaf(k.y, s, k.x);
    float t2  = fmaf(k.w, s, k.z);
    float s1  = fmaf(s2m, t2, t1);
    float w2  = s1 * s1;
    float q4  = gma * s1;
    float w4  = w2 * w2;
    s = fmaf(-q4, w4, s1);
    ps_o = fmaxf(s1 - sp, 0.0f);
    pc_o = q4 * w4;
}

struct KC { float inv, x1, x1sq, x1_2, two_x1cu, five_x1sq, four_x1; };

// per-step cubic coefficients (identical numerics to round-8 phase 1)
// note: P=E=0 yields exactly (0,1,0,0) => zero-padding needs no special case.
__device__ __forceinline__ f32x4 mkk(float P, float Ev, const KC c,
                                     float& pn_o, float& en_o) {
    float d  = P - Ev;
    float pn = fmaxf(d, 0.f), en = fmaxf(-d, 0.f);
    float up = pn * c.inv, un = en * c.inv;
    float tp = up * fmaf(up * up, -(1.f/3.f), 1.f);
    float tn = un * fmaf(un * un, -(1.f/3.f), 1.f);
    float al = tp * c.inv, be = tn * c.inv;
    float a2 = al * al,  a3v = a2 * al;
    float b2 = be * be,  b3v = b2 * be;
    float e2 = fmaf(-be, c.x1, 1.f);
    float k0 = tp * c.x1;
    float k1 = 1.f - a2 * c.x1sq - (c.x1_2 * be * e2 + c.two_x1cu * b3v);
    float k2 = (a3v * c.x1sq - al) - (c.x1_2 * b2 - be * e2 - c.five_x1sq * b3v);
    float k3 = a2 + b2 - c.four_x1 * b3v;
    pn_o = pn; en_o = en;
    return (f32x4){k0, k1, k2, k3};
}

__global__ __launch_bounds__(TPB, 4) void scan_h512(
        const float* __restrict__ x, const float* __restrict__ x1p,
        f32x4* __restrict__ pspc4, f32x4* __restrict__ s4,
        float* __restrict__ partials) {
    __shared__ f32x4 tk[16 * NCK];              // 33024 B half k-tile
    __shared__ f32x4 mapA[NMAP];                // 5632 B map coeffs d0..d3
    __shared__ f32x4 mapB[NMAP];                // 5632 B map coeffs d4..d7
    __shared__ float red[8 * NWAVE];            // total ~44.5 KB -> 2 blk/CU

    const int tid  = threadIdx.x;
    const int lane = tid & 63;
    const int wid  = tid >> 6;
    const int b    = blockIdx.x;

    const float x1 = x1p[0];
    KC c;
    c.inv = 1.0f / x1; c.x1 = x1; c.x1sq = x1 * x1; c.x1_2 = 2.0f * x1;
    c.two_x1cu = 2.0f * x1 * c.x1sq; c.five_x1sq = 5.0f * c.x1sq;
    c.four_x1 = 4.0f * x1;
    const float gma = 64.0f / (6561.0f * c.x1sq * c.x1sq);   // perc = gma*s1^5
    const float cen = (184.0f / 350.0f) * x1;   // sigma domain center
    const float hw  = (208.0f / 350.0f) * x1;   // sigma domain half-width
    const float ihw = 1.0f / hw;

    const f32x4* __restrict__ x4 = (const f32x4*)x;   // one f32x4 == 2 steps
    float spn = 0.f, sen = 0.f, qpn = 0.f, qen = 0.f;

    // ---- phase 1 (one map per thread, 352 builders of 512): build degree-7
    //      16-step maps directly from x; EVEN main maps deposit their 16
    //      per-step cubics (chunk steps 0..15) into tk + pn/en stats. ----
    if (tid < NMAP) {
        const f32x4 z4 = (f32x4){0.f, 0.f, 0.f, 0.f};
        const int m = tid - WUMAP;               // map index in [-96, 256)
        const long gp = (long)b * 2048 + 8L * m;
        f32x4 w[8];
        #pragma unroll
        for (int q = 0; q < 8; ++q) {
            const long g = gp + q;
            w[q] = (g >= 0) ? x4[g] : z4;
        }

        float sv[8];
        {
            const float ND[8] = { CC1,  CC3,  CC5,  CC7, -CC7, -CC5, -CC3, -CC1};
            #pragma unroll
            for (int j = 0; j < 8; ++j) sv[j] = fmaf(hw, ND[j], cen);
        }
        const bool depositm = (m >= 0) && ((m & 1) == 0);
        const int  lcol     = m >> 1;            // owning chunk for even maps
        #pragma unroll
        for (int q = 0; q < 8; ++q) {            // 8 pairs = 16 steps
            float pn0, en0, pn1, en1;
            const f32x4 kA = mkk(w[q].x, w[q].y, c, pn0, en0);
            const f32x4 kB = mkk(w[q].z, w[q].w, c, pn1, en1);
            #pragma unroll
            for (int j = 0; j < 8; ++j) {        // 8 independent node chains
                stepk(sv[j], kA, gma);
                stepk(sv[j], kB, gma);
            }
            if (depositm) {                      // chunk steps 2q, 2q+1
                spn += pn0 + pn1; sen += en0 + en1;
                qpn = fmaf(pn0, pn0, fmaf(pn1, pn1, qpn));
                qen = fmaf(en0, en0, fmaf(en1, en1, qen));
                tk[(2 * q) * NCK + lcol]     = kA;
                tk[(2 * q + 1) * NCK + lcol] = kB;
            }
        }
        float v[8];
        #pragma unroll
        for (int j = 0; j < 8; ++j) v[j] = (sv[j] - cen) * ihw;
        const float e0 = v[0] + v[7], e1 = v[1] + v[6];
        const float e2 = v[2] + v[5], e3 = v[3] + v[4];
        const float o0 = v[0] - v[7], o1 = v[1] - v[6];
        const float o2 = v[2] - v[5], o3 = v[3] - v[4];
        const float a0 = 0.125f * (e0 + e1 + e2 + e3);
        const float a1 = 0.25f * (o0*CC1 + o1*CC3 + o2*CC5 + o3*CC7);
        const float a2 = 0.25f * ((e0 - e3)*CC2 + (e1 - e2)*CC6);
        const float a3 = 0.25f * (o0*CC3 - o1*CC7 - o2*CC1 - o3*CC5);
        const float a4 = 0.25f * CC4 * ((e0 + e3) - (e1 + e2));
        const float a5 = 0.25f * (o0*CC5 - o1*CC1 + o2*CC7 + o3*CC3);
        const float a6 = 0.25f * ((e0 - e3)*CC6 - (e1 - e2)*CC2);
        const float a7 = 0.25f * (o0*CC7 - o1*CC5 + o2*CC3 - o3*CC1);
        const int slot = (tid >> 1) + ((tid & 1) ? HODD : 0);
        mapA[slot] = (f32x4){a0 - a2 + a4 - a6,
                             a1 - 3.0f*a3 + 5.0f*a5 - 7.0f*a7,
                             2.0f*a2 - 8.0f*a4 + 18.0f*a6,
                             4.0f*a3 - 20.0f*a5 + 56.0f*a7};
        mapB[slot] = (f32x4){8.0f*a4 - 48.0f*a6,
                             16.0f*a5 - 112.0f*a7,
                             32.0f*a6,
                             64.0f*a7};
    }
    __syncthreads();

    // ---- phase 2a + 2b-h1 (threads 0..127 = waves 0,1) ----
    float aps = 0.f, apc = 0.f, qps = 0.f, qpc = 0.f;
    if (tid < CPB) {
        const int l = tid;
        const long gstart = ((long)b * CPB + l) * LCH;
        const float s0 = (gstart >= WUP) ? 0.47f * x1 : 0.0f;  // attractor / exact-0
        float sg = (s0 - cen) * ihw;

        // warm-up sigma-scan: 12 stages x 8 maps, 3 dep levels each
        f32x4 A[8], B[8];
        #pragma unroll 1
        for (int st = 0; st < WSTO; ++st) {
            const int base = l + 4 * st;         // slot-split layout
            #pragma unroll
            for (int u = 0; u < 8; ++u)
                A[u] = mapA[base + (u >> 1) + ((u & 1) ? HODD : 0)];
            #pragma unroll
            for (int u = 0; u < 8; ++u)
                B[u] = mapB[base + (u >> 1) + ((u & 1) ? HODD : 0)];
            #pragma unroll
            for (int u = 0; u < 8; ++u) {        // Estrin deg-7: 3 levels
                const float s2  = sg * sg;
                const float p0  = fmaf(A[u].y, sg, A[u].x);
                const float p1  = fmaf(A[u].w, sg, A[u].z);
                const float p2  = fmaf(B[u].y, sg, B[u].x);
                const float p3  = fmaf(B[u].w, sg, B[u].z);
                const float s4v = s2 * s2;
                const float q0  = fmaf(p1, s2, p0);
                const float q1  = fmaf(p3, s2, p2);
                sg = fmaf(q1, s4v, q0);
            }
        }
        float s = fmaf(hw, sg, cen);

        // main scan, first half (chunk steps 0..15 from tk)
        const size_t chunk = (size_t)b * CPB + l;
        #pragma unroll 1
        for (int mst = 0; mst < 2; ++mst) {
            f32x4 K[8];
            const int rbase = (mst << 3) * NCK + l;
            #pragma unroll
            for (int u = 0; u < 8; ++u) K[u] = tk[rbase + u * NCK];
            float psv[8], pcv[8], svv[8];
            #pragma unroll
            for (int u = 0; u < 8; ++u) {
                stepk_m(s, K[u], gma, psv[u], pcv[u]);
                svv[u] = s;
            }
            #pragma unroll
            for (int u = 0; u < 8; ++u) {
                aps += psv[u]; apc += pcv[u];
                qps = fmaf(psv[u], psv[u], qps); qpc = fmaf(pcv[u], pcv[u], qpc);
            }
            const size_t pb = chunk * 16 + 4 * mst;
            pspc4[pb + 0] = (f32x4){psv[0], pcv[0], psv[1], pcv[1]};
            pspc4[pb + 1] = (f32x4){psv[2], pcv[2], psv[3], pcv[3]};
            pspc4[pb + 2] = (f32x4){psv[4], pcv[4], psv[5], pcv[5]};
            pspc4[pb + 3] = (f32x4){psv[6], pcv[6], psv[7], pcv[7]};
            const size_t sb = chunk * 8 + 2 * mst;
            s4[sb]     = (f32x4){svv[0], svv[1], svv[2], svv[3]};
            s4[sb + 1] = (f32x4){svv[4], svv[5], svv[6], svv[7]};
        }
        // carry state to h2 via sg (register survives; threads identical)
        sg = s;                                  // reuse reg: holds s now
        __syncthreads();                         // (1) h1 reads done

        // wait for restage (done by all threads incl. these below) -- but
        // these 128 threads must ALSO participate in restage; fall through.
        // (restage + barrier happen outside this if; s kept in sg)
        // store s into aps-adjacent slot not needed: keep in register.
        // -- we exit the if with sg = s_after_h1 --
        aps = aps; // no-op to keep structure clear
        // NOTE: the actual h2 runs after the global restage below.
        // We stash s in a per-thread register that persists.
        // (handled via 'scarry' below)
    }
    // carry register for h2 (only meaningful for tid<128)
    float scarry = 0.0f;
    if (tid < CPB) {
        // recover s from the sg alias: recompute not possible -> use shuffle-free
        // trick: we simply re-enter the region; sg was local. Instead, stash:
        // (sg went out of scope; restructure: we saved it below.)
        scarry = 0.0f;  // placeholder, overwritten in the re-merged flow below
    }
    // ---- The above if-block structure cannot carry 's' out cleanly; the
    //      compiler-friendly restructuring: redo with explicit carry. ----
    // (see scarry2 path)
    __syncthreads();                             // (2) align all threads

    // ---- phase 3: restage chunk steps 16..31 into tk (all 512 threads) ----
    {
        const int l  = tid >> 2;                 // chunk 0..127
        const int qq = tid & 3;                  // 4 threads per chunk
        const long gp = (long)b * 2048 + 16L * l + 8 + 2 * qq;
        const f32x4 w0 = x4[gp];
        const f32x4 w1 = x4[gp + 1];
        float pn0, en0, pn1, en1, pn2, en2, pn3, en3;
        const f32x4 k0 = mkk(w0.x, w0.y, c, pn0, en0);
        const f32x4 k1 = mkk(w0.z, w0.w, c, pn1, en1);
        const f32x4 k2 = mkk(w1.x, w1.y, c, pn2, en2);
        const f32x4 k3 = mkk(w1.z, w1.w, c, pn3, en3);
        const int r = 4 * qq;
        tk[(r + 0) * NCK + l] = k0;
        tk[(r + 1) * NCK + l] = k1;
        tk[(r + 2) * NCK + l] = k2;
        tk[(r + 3) * NCK + l] = k3;
        spn += pn0 + pn1 + pn2 + pn3;
        sen += en0 + en1 + en2 + en3;
        qpn = fmaf(pn0, pn0, fmaf(pn1, pn1, fmaf(pn2, pn2, fmaf(pn3, pn3, qpn))));
        qen = fmaf(en0, en0, fmaf(en1, en1, fmaf(en2, en2, fmaf(en3, en3, qen))));
    }
    __syncthreads();                             // (3) restage visible

    // ---- phase 2b-h2 (threads 0..127): chunk steps 16..31 ----
    if (tid < CPB) {
        const int l = tid;
        const size_t chunk = (size_t)b * CPB + l;
        // reload state: s after step 15 was stored to s4[chunk*8+3].w
        float s = s4[chunk * 8 + 3].w;
        #pragma unroll 1
        for (int mst = 2; mst < 4; ++mst) {
            f32x4 K[8];
            const int rbase = ((mst - 2) << 3) * NCK + l;
            #pragma unroll
            for (int u = 0; u < 8; ++u) K[u] = tk[rbase + u * NCK];
            float psv[8], pcv[8], svv[8];
            #pragma unroll
            for (int u = 0; u < 8; ++u) {
                stepk_m(s, K[u], gma, psv[u], pcv[u]);
                svv[u] = s;
            }
            #pragma unroll
            for (int u = 0; u < 8; ++u) {
                aps += psv[u]; apc += pcv[u];
                qps = fmaf(psv[u], psv[u], qps); qpc = fmaf(pcv[u], pcv[u], qpc);
            }
            const size_t pb = chunk * 16 + 4 * mst;
            pspc4[pb + 0] = (f32x4){psv[0], pcv[0], psv[1], pcv[1]};
            pspc4[pb + 1] = (f32x4){psv[2], pcv[2], psv[3], pcv[3]};
            pspc4[pb + 2] = (f32x4){psv[4], pcv[4], psv[5], pcv[5]};
            pspc4[pb + 3] = (f32x4){psv[6], pcv[6], psv[7], pcv[7]};
            const size_t sb = chunk * 8 + 2 * mst;
            s4[sb]     = (f32x4){svv[0], svv[1], svv[2], svv[3]};
            s4[sb + 1] = (f32x4){svv[4], svv[5], svv[6], svv[7]};
        }
    }

    // ---- block reduction of 8 stat accumulators ----
    float vals[8] = {spn, sen, aps, apc, qpn, qen, qps, qpc};
    #pragma unroll
    for (int k = 0; k < 8; ++k) {
        float v = vals[k];
        #pragma unroll
        for (int off = 32; off > 0; off >>= 1) v += __shfl_down(v, off, 64);
        if (lane == 0) red[k * NWAVE + wid] = v;
    }
    __syncthreads();
    if (tid < 8) {
        float v = 0.f;
        #pragma unroll
        for (int wv = 0; wv < NWAVE; ++wv) v += red[tid * NWAVE + wv];
        partials[b * 8 + tid] = v;
    }
}

// ---- stats finalize folded in + fused normalize/assemble (unchanged) ----
__global__ __launch_bounds__(256) void normalize_stats(
        const float* __restrict__ x, const f32x4* __restrict__ pspc4,
        const float* __restrict__ pA, f32x4* __restrict__ out4,
        int nA, int Thalf, int T) {
    __shared__ float red[256];
    __shared__ float sst[8];
    const int tid = threadIdx.x;
    {   // components: 0 pn,1 en,2 ps,3 pc (sums); 4..7 squares
        const int c = tid & 7;
        float v = 0.f;
        for (int i = tid >> 3; i < nA; i += 32) v += pA[i * 8 + c];
        red[tid] = v;
        __syncthreads();
        for (int off = 128; off >= 8; off >>= 1) {
            if (tid < off) red[tid] += red[tid + off];
            __syncthreads();
        }
        if (tid == 0) {
            const float invT = 1.0f / (float)T;
            #pragma unroll
            for (int k = 0; k < 4; ++k) {
                float mu  = red[k] * invT;
                float var = fmaxf(fmaf(-mu, mu, red[4 + k] * invT), 0.0f);
                sst[k]     = mu;
                sst[4 + k] = (var > 0.0f) ? rsqrtf(var) : 0.0f;
            }
        }
        __syncthreads();
    }
    const float mu0 = sst[0], mu1 = sst[1], mu2 = sst[2], mu3 = sst[3];
    const float is0 = sst[4], is1 = sst[5], is2 = sst[6], is3 = sst[7];
    const f32x4* __restrict__ x4 = (const f32x4*)x;
    for (int i = blockIdx.x * 256 + tid; i < Thalf; i += 1024 * 256) {
        f32x4 xv = x4[i];
        f32x4 pq = pspc4[i];
        float d0 = xv.x - xv.y, d1 = xv.z - xv.w;
        out4[2 * i]     = (f32x4){(fmaxf(d0, 0.f) - mu0) * is0,
                                  (fmaxf(-d0, 0.f) - mu1) * is1,
                                  (pq.x - mu2) * is2,
                                  (pq.y - mu3) * is3};
        out4[2 * i + 1] = (f32x4){(fmaxf(d1, 0.f) - mu0) * is0,
                                  (fmaxf(-d1, 0.f) - mu1) * is1,
                                  (pq.z - mu2) * is2,
                                  (pq.w - mu3) * is3};
    }
}

// ---------------- round-1 fallback (proven; own WARMUP=2048, s0=0) ----------
#define L_CHUNK  128
#define FB_WARMUP 2048
__device__ __forceinline__ float inv1p_fb(float a) {
    float i1 = 1.0f - a;
    float i2 = fmaf(-a, i1, 1.0f);
    return fmaf(-a, i2, 1.0f);
}
struct SCfb { float x1, inv_x1, c49; };
__device__ __forceinline__ void scan_step_fb(float& s, float P, float E, const SCfb c,
                                             float& pn, float& en, float& ps, float& pc) {
    float d = P - E;
    float pn_ = fmaxf(d, 0.0f), en_ = fmaxf(-d, 0.0f);
    float up = pn_ * c.inv_x1;
    float tp = up * fmaf(up * up, -(1.0f / 3.0f), 1.0f);
    float un = en_ * c.inv_x1;
    float tn = un * fmaf(un * un, -(1.0f / 3.0f), 1.0f);
    float r = s * c.inv_x1;
    float ps_ = (tp * c.x1) * fmaf(-r, r, 1.0f) * inv1p_fb(r * tp);
    float es_ = (s * (2.0f - r)) * tn * inv1p_fb((1.0f - r) * tn);
    float s1 = s + ps_ - es_;
    float z = s1 * c.c49, z2 = z * z, v = z2 * z2;
    float t = fmaf(v, fmaf(v, 0.15625f, -0.25f), 1.0f);
    float s2 = s1 * t;
    pn = pn_; en = en_; ps = ps_; pc = s1 - s2; s = s2;
}
__global__ __launch_bounds__(256) void scan_kernel_fb(
        const float* __restrict__ x, const float* __restrict__ x1ptr,
        float* __restrict__ out, float* __restrict__ s_store,
        float* __restrict__ partials, int T) {
    const int c = blockIdx.x * blockDim.x + threadIdx.x;
    const int nchunks = (T + L_CHUNK - 1) / L_CHUNK;
    SCfb cc; cc.x1 = x1ptr[0]; cc.inv_x1 = 1.0f / cc.x1; cc.c49 = (4.0f / 9.0f) * cc.inv_x1;
    float s1a[4] = {0.f, 0.f, 0.f, 0.f};
    float s2a[4] = {0.f, 0.f, 0.f, 0.f};
    if (c < nchunks) {
        const int g0 = c * L_CHUNK;
        const int g1 = min(g0 + L_CHUNK, T);
        const int w0 = max(g0 - FB_WARMUP, 0);
        float s = 0.0f; float pn, en, ps, pc;
        const float2* __restrict__ x2 = (const float2*)x;
        for (int t = w0; t < g0; ++t) { float2 xv = x2[t]; scan_step_fb(s, xv.x, xv.y, cc, pn, en, ps, pc); }
        float4* __restrict__ out4 = (float4*)out;
        for (int t = g0; t < g1; ++t) {
            float2 xv = x2[t];
            scan_step_fb(s, xv.x, xv.y, cc, pn, en, ps, pc);
            out4[t] = make_float4(pn, en, ps, pc);
            s_store[t] = s;
            s1a[0] += pn; s1a[1] += en; s1a[2] += ps; s1a[3] += pc;
            s2a[0] = fmaf(pn, pn, s2a[0]); s2a[1] = fmaf(en, en, s2a[1]);
            s2a[2] = fmaf(ps, ps, s2a[2]); s2a[3] = fmaf(pc, pc, s2a[3]);
        }
    }
    __shared__ float red[256];
    float vals[8] = {s1a[0], s1a[1], s1a[2], s1a[3], s2a[0], s2a[1], s2a[2], s2a[3]};
    for (int k = 0; k < 8; ++k) {
        red[threadIdx.x] = vals[k];
        __syncthreads();
        for (int off = 128; off > 0; off >>= 1) {
            if ((int)threadIdx.x < off) red[threadIdx.x] += red[threadIdx.x + off];
            __syncthreads();
        }
        if (threadIdx.x == 0) partials[blockIdx.x * 8 + k] = red[0];
        __syncthreads();
    }
}
__global__ __launch_bounds__(64) void finalize_fb(
        const float* __restrict__ partials, float* __restrict__ stats, int nblk, int T) {
    const int lane = threadIdx.x;
    float v[8] = {0.f, 0.f, 0.f, 0.f, 0.f, 0.f, 0.f, 0.f};
    for (int b = lane; b < nblk; b += 64)
        for (int k = 0; k < 8; ++k) v[k] += partials[b * 8 + k];
    #pragma unroll
    for (int k = 0; k < 8; ++k)
        for (int off = 32; off > 0; off >>= 1) v[k] += __shfl_down(v[k], off, 64);
    if (lane == 0) {
        const float invT = 1.0f / (float)T;
        for (int k = 0; k < 4; ++k) {
            float mu = v[k] * invT;
            float var = fmaxf(fmaf(-mu, mu, v[k + 4] * invT), 0.0f);
            stats[k] = mu;
            stats[4 + k] = (var > 0.0f) ? rsqrtf(var) : 0.0f;
        }
    }
}
__global__ __launch_bounds__(256) void normalize_fb(
        float* __restrict__ out, const float* __restrict__ stats, int T) {
    const int t = blockIdx.x * blockDim.x + threadIdx.x;
    if (t >= T) return;
    const float4 mu = *(const float4*)stats;
    const float4 is = *(const float4*)(stats + 4);
    float4* o4 = (float4*)out;
    float4 v = o4[t];
    v.x = (v.x - mu.x) * is.x; v.y = (v.y - mu.y) * is.y;
    v.z = (v.z - mu.z) * is.z; v.w = (v.w - mu.w) * is.w;
    o4[t] = v;
}
// -----------------------------------------------------------------------------

extern "C" void kernel_launch(void* const* d_in, const int* in_sizes, int n_in,
                              void* d_out, int out_size, void* d_ws, size_t ws_size,
                              hipStream_t stream) {
    const float* x  = (const float*)d_in[0];
    const float* x1 = (const float*)d_in[1];
    const int T = in_sizes[0] / 2;

    float* out     = (float*)d_out;                // (T,4)
    float* s_store = out + 4 * (size_t)T;          // (T,)

    const int nblk = T / BSTEPS;                   // scan blocks (fast path)

    float* pA = (float*)d_ws;                      // nblk*8 floats (<=4096)
    const size_t pq_off = 4608;                    // f32x4-aligned float offset
    const size_t need = (pq_off + 2 * (size_t)T) * sizeof(float);

    const bool fast = (T % BSTEPS == 0) && nblk >= 1 && nblk <= 512 &&
                      (ws_size >= need);

    if (fast) {
        f32x4* pspc4 = (f32x4*)((float*)d_ws + pq_off);
        scan_h512<<<nblk, TPB, 0, stream>>>(x, x1, pspc4, (f32x4*)s_store, pA);
        normalize_stats<<<1024, 256, 0, stream>>>(x, pspc4, pA,
                                                  (f32x4*)out, nblk, T / 2, T);
    } else {
        float* stats    = (float*)d_ws;
        float* partials = stats + 8;
        const int nchunks = (T + L_CHUNK - 1) / L_CHUNK;
        const int nblkA = (nchunks + 255) / 256;
        scan_kernel_fb<<<nblkA, 256, 0, stream>>>(x, x1, out, s_store, partials, T);
        finalize_fb<<<1, 64, 0, stream>>>(partials, stats, nblkA, T);
        normalize_fb<<<(T + 255) / 256, 256, 0, stream>>>(out, stats, T);
    }
}

// Round 8
// 111.013 us; speedup vs baseline: 1.0531x; 1.0476x over previous
//
#include <hip/hip_runtime.h>

// GR4J production-store scan, parallelized by contraction.
//
// Round-16 == Round-14 resubmitted again (two consecutive broker-level
// "MI355X container failed twice" errors; source re-audited: all LDS/global
// indices in range, uniform barriers, no graph-capture violations — no
// mechanism for a kernel-induced container death).
//
// Round-14: consolidation. Six-round accounting: dur = fill_ws(44.5, harness
// poison, HBM-bound) + fill_out(~7) + gaps + normalize + scan; scan has been
// <44us (below top-5 cutoff) for 3 rounds; container noise +-6us swamps
// further scan deltas. Remove the remaining CERTAIN waste:
//   - full 32-row k-tile again (77.6KB fits 2 blk/CU; r13's half-tile +
//     restage + mid-scan s reload from HBM was pure overhead) — s carried
//     in register across all 4 main stages, 2 fewer barriers.
//   - build does NO stats; phase 2b re-reads its chunk's x pairs (L2-hot)
//     for pn/en, writes UNNORMALIZED out rows directly + s_store, owns all
//     8 stat accumulators. pspc4 workspace eliminated (16KB partials only).
//   - normalize: partials-reduce + in-place scale of out (67MB, was 84MB —
//     no x read, no pspc4 read).
//   - map width/numerics IDENTICAL to r11-13 (zero accuracy risk).
// Fallback to the round-1 kernel for odd shapes.

typedef float f32x4 __attribute__((ext_vector_type(4)));

#define LCH      32            // main steps per chunk
#define CPB      128           // chunks per block
#define TPB      512           // threads per block (8 waves)
#define BSTEPS   4096          // LCH*CPB main steps per block
#define WUP      1536          // warm-up steps
#define WUMAP    96            // WUP/16 warm maps per chunk window
#define WSTO     12            // WUMAP/8 warm stages
#define NMAP     352           // map window union = 2*(CPB-1)+WUMAP (+pad even)
#define HODD     176           // odd-map slot offset = NMAP/2
#define NCK      129           // k-tile padded cols (32 rows; 128 used)
#define NWAVE    8             // TPB/64

// Chebyshev node values cos((2j+1)pi/16) and DCT constants
#define CC1 0.98078528f
#define CC2 0.92387953f
#define CC3 0.83146961f
#define CC4 0.70710678f
#define CC5 0.55557023f
#define CC6 0.38268343f
#define CC7 0.19509032f

// one exact cubic+quintic step, warm-up flavor (state only)
__device__ __forceinline__ void stepk(float& s, const f32x4 k, float gma) {
    float s2m = s * s;
    float t1  = fmaf(k.y, s, k.x);
    float t2  = fmaf(k.w, s, k.z);
    float s1  = fmaf(s2m, t2, t1);
    float w2  = s1 * s1;
    float q4  = gma * s1;
    float w4  = w2 * w2;
    s = fmaf(-q4, w4, s1);
}

// main flavor: also emit ps (= relu(s1 - s_prev), exact) and pc (= gma*s1^5)
__device__ __forceinline__ void stepk_m(float& s, const f32x4 k, float gma,
                                        float& ps_o, float& pc_o) {
    float sp  = s;
    float s2m = s * s;
    float t1  = fmaf(k.y, s, k.x);
    float t2  = fmaf(k.w, s, k.z);
    float s1  = fmaf(s2m, t2, t1);
    float w2  = s1 * s1;
    float q4  = gma * s1;
    float w4  = w2 * w2;
    s = fmaf(-q4, w4, s1);
    ps_o = fmaxf(s1 - sp, 0.0f);
    pc_o = q4 * w4;
}

struct KC { float inv, x1, x1sq, x1_2, two_x1cu, five_x1sq, four_x1; };

// per-step cubic coefficients (identical numerics to round-8 phase 1)
// note: P=E=0 yields exactly (0,1,0,0) => zero-padding needs no special case.
__device__ __forceinline__ f32x4 mkk(float P, float Ev, const KC c) {
    float d  = P - Ev;
    float pn = fmaxf(d, 0.f), en = fmaxf(-d, 0.f);
    float up = pn * c.inv, un = en * c.inv;
    float tp = up * fmaf(up * up, -(1.f/3.f), 1.f);
    float tn = un * fmaf(un * un, -(1.f/3.f), 1.f);
    float al = tp * c.inv, be = tn * c.inv;
    float a2 = al * al,  a3v = a2 * al;
    float b2 = be * be,  b3v = b2 * be;
    float e2 = fmaf(-be, c.x1, 1.f);
    float k0 = tp * c.x1;
    float k1 = 1.f - a2 * c.x1sq - (c.x1_2 * be * e2 + c.two_x1cu * b3v);
    float k2 = (a3v * c.x1sq - al) - (c.x1_2 * b2 - be * e2 - c.five_x1sq * b3v);
    float k3 = a2 + b2 - c.four_x1 * b3v;
    return (f32x4){k0, k1, k2, k3};
}

__global__ __launch_bounds__(TPB, 4) void scan_fused(
        const float* __restrict__ x, const float* __restrict__ x1p,
        f32x4* __restrict__ out4, f32x4* __restrict__ s4,
        float* __restrict__ partials) {
    __shared__ f32x4 tk[32 * NCK];              // 66048 B full k-tile
    __shared__ f32x4 mapA[NMAP];                // 5632 B map coeffs d0..d3
    __shared__ f32x4 mapB[NMAP];                // 5632 B map coeffs d4..d7
    __shared__ float red[8 * NWAVE];            // total ~77.6 KB -> 2 blk/CU

    const int tid  = threadIdx.x;
    const int lane = tid & 63;
    const int wid  = tid >> 6;
    const int b    = blockIdx.x;

    const float x1 = x1p[0];
    KC c;
    c.inv = 1.0f / x1; c.x1 = x1; c.x1sq = x1 * x1; c.x1_2 = 2.0f * x1;
    c.two_x1cu = 2.0f * x1 * c.x1sq; c.five_x1sq = 5.0f * c.x1sq;
    c.four_x1 = 4.0f * x1;
    const float gma = 64.0f / (6561.0f * c.x1sq * c.x1sq);   // perc = gma*s1^5
    const float cen = (184.0f / 350.0f) * x1;   // sigma domain center
    const float hw  = (208.0f / 350.0f) * x1;   // sigma domain half-width
    const float ihw = 1.0f / hw;

    const f32x4* __restrict__ x4 = (const f32x4*)x;   // one f32x4 == 2 steps

    // ---- phase 1 (one map per thread, 352 builders of 512): build degree-7
    //      16-step maps directly from x; main maps deposit their 16 per-step
    //      cubics into the full tk tile. No stats here. ----
    if (tid < NMAP) {
        const f32x4 z4 = (f32x4){0.f, 0.f, 0.f, 0.f};
        const int m = tid - WUMAP;               // map index in [-96, 256)
        const long gp = (long)b * 2048 + 8L * m;
        f32x4 w[8];
        #pragma unroll
        for (int q = 0; q < 8; ++q) {
            const long g = gp + q;
            w[q] = (g >= 0) ? x4[g] : z4;
        }

        float sv[8];
        {
            const float ND[8] = { CC1,  CC3,  CC5,  CC7, -CC7, -CC5, -CC3, -CC1};
            #pragma unroll
            for (int j = 0; j < 8; ++j) sv[j] = fmaf(hw, ND[j], cen);
        }
        const bool mainm = (m >= 0);
        const int  lcol  = m >> 1;               // owning chunk (main maps)
        const int  rbase = (m & 1) << 4;         // rows 0..15 or 16..31
        #pragma unroll
        for (int q = 0; q < 8; ++q) {            // 8 pairs = 16 steps
            const f32x4 kA = mkk(w[q].x, w[q].y, c);
            const f32x4 kB = mkk(w[q].z, w[q].w, c);
            #pragma unroll
            for (int j = 0; j < 8; ++j) {        // 8 independent node chains
                stepk(sv[j], kA, gma);
                stepk(sv[j], kB, gma);
            }
            if (mainm) {
                const int r = rbase + 2 * q;
                tk[r * NCK + lcol]       = kA;
                tk[(r + 1) * NCK + lcol] = kB;
            }
        }
        float v[8];
        #pragma unroll
        for (int j = 0; j < 8; ++j) v[j] = (sv[j] - cen) * ihw;
        const float e0 = v[0] + v[7], e1 = v[1] + v[6];
        const float e2 = v[2] + v[5], e3 = v[3] + v[4];
        const float o0 = v[0] - v[7], o1 = v[1] - v[6];
        const float o2 = v[2] - v[5], o3 = v[3] - v[4];
        const float a0 = 0.125f * (e0 + e1 + e2 + e3);
        const float a1 = 0.25f * (o0*CC1 + o1*CC3 + o2*CC5 + o3*CC7);
        const float a2 = 0.25f * ((e0 - e3)*CC2 + (e1 - e2)*CC6);
        const float a3 = 0.25f * (o0*CC3 - o1*CC7 - o2*CC1 - o3*CC5);
        const float a4 = 0.25f * CC4 * ((e0 + e3) - (e1 + e2));
        const float a5 = 0.25f * (o0*CC5 - o1*CC1 + o2*CC7 + o3*CC3);
        const float a6 = 0.25f * ((e0 - e3)*CC6 - (e1 - e2)*CC2);
        const float a7 = 0.25f * (o0*CC7 - o1*CC5 + o2*CC3 - o3*CC1);
        const int slot = (tid >> 1) + ((tid & 1) ? HODD : 0);
        mapA[slot] = (f32x4){a0 - a2 + a4 - a6,
                             a1 - 3.0f*a3 + 5.0f*a5 - 7.0f*a7,
                             2.0f*a2 - 8.0f*a4 + 18.0f*a6,
                             4.0f*a3 - 20.0f*a5 + 56.0f*a7};
        mapB[slot] = (f32x4){8.0f*a4 - 48.0f*a6,
                             16.0f*a5 - 112.0f*a7,
                             32.0f*a6,
                             64.0f*a7};
    }
    __syncthreads();

    // ---- phase 2 (threads 0..127): warm sigma-scan then main scan with
    //      direct unnormalized out writes; s carried in register throughout.
    float spn = 0.f, sen = 0.f, aps = 0.f, apc = 0.f;
    float qpn = 0.f, qen = 0.f, qps = 0.f, qpc = 0.f;
    if (tid < CPB) {
        const int l = tid;
        const long gstart = ((long)b * CPB + l) * LCH;
        const float s0 = (gstart >= WUP) ? 0.47f * x1 : 0.0f;  // attractor / exact-0
        float sg = (s0 - cen) * ihw;

        // warm-up: 12 stages x 8 maps, 3 dep levels each
        f32x4 A[8], B[8];
        #pragma unroll 1
        for (int st = 0; st < WSTO; ++st) {
            const int base = l + 4 * st;         // slot-split layout
            #pragma unroll
            for (int u = 0; u < 8; ++u)
                A[u] = mapA[base + (u >> 1) + ((u & 1) ? HODD : 0)];
            #pragma unroll
            for (int u = 0; u < 8; ++u)
                B[u] = mapB[base + (u >> 1) + ((u & 1) ? HODD : 0)];
            #pragma unroll
            for (int u = 0; u < 8; ++u) {        // Estrin deg-7: 3 levels
                const float s2  = sg * sg;
                const float p0  = fmaf(A[u].y, sg, A[u].x);
                const float p1  = fmaf(A[u].w, sg, A[u].z);
                const float p2  = fmaf(B[u].y, sg, B[u].x);
                const float p3  = fmaf(B[u].w, sg, B[u].z);
                const float s4v = s2 * s2;
                const float q0  = fmaf(p1, s2, p0);
                const float q1  = fmaf(p3, s2, p2);
                sg = fmaf(q1, s4v, q0);
            }
        }
        float s = fmaf(hw, sg, cen);

        // main scan: 4 stages x 8 steps; pn/en from L2-hot x re-read;
        // writes full unnormalized out rows + s_store.
        const size_t chunk = (size_t)b * CPB + l;
        const long   P0    = (long)b * 2048 + 16L * l;   // chunk's first pair
        #pragma unroll 1
        for (int mst = 0; mst < 4; ++mst) {
            f32x4 K[8];
            const int rb = (mst << 3) * NCK + l;
            #pragma unroll
            for (int u = 0; u < 8; ++u) K[u] = tk[rb + u * NCK];
            f32x4 xw[4];
            #pragma unroll
            for (int q = 0; q < 4; ++q) xw[q] = x4[P0 + 4 * mst + q];
            float sv8[8];
            #pragma unroll
            for (int u = 0; u < 8; ++u) {
                float ps, pc;
                stepk_m(s, K[u], gma, ps, pc);
                sv8[u] = s;
                const f32x4 wv = xw[u >> 1];
                const float d  = (u & 1) ? (wv.z - wv.w) : (wv.x - wv.y);
                const float pn = fmaxf(d, 0.f), en = fmaxf(-d, 0.f);
                out4[chunk * 32 + 8 * mst + u] = (f32x4){pn, en, ps, pc};
                spn += pn; sen += en; aps += ps; apc += pc;
                qpn = fmaf(pn, pn, qpn); qen = fmaf(en, en, qen);
                qps = fmaf(ps, ps, qps); qpc = fmaf(pc, pc, qpc);
            }
            const size_t sb = chunk * 8 + 2 * mst;
            s4[sb]     = (f32x4){sv8[0], sv8[1], sv8[2], sv8[3]};
            s4[sb + 1] = (f32x4){sv8[4], sv8[5], sv8[6], sv8[7]};
        }
    }

    // ---- block reduction of 8 stat accumulators ----
    float vals[8] = {spn, sen, aps, apc, qpn, qen, qps, qpc};
    #pragma unroll
    for (int k = 0; k < 8; ++k) {
        float v = vals[k];
        #pragma unroll
        for (int off = 32; off > 0; off >>= 1) v += __shfl_down(v, off, 64);
        if (lane == 0) red[k * NWAVE + wid] = v;
    }
    __syncthreads();
    if (tid < 8) {
        float v = 0.f;
        #pragma unroll
        for (int wv = 0; wv < NWAVE; ++wv) v += red[tid * NWAVE + wv];
        partials[b * 8 + tid] = v;
    }
}

// ---- stats finalize + in-place normalize of out (no x, no pspc4) ----
__global__ __launch_bounds__(256) void normalize_stats(
        const float* __restrict__ pA, f32x4* __restrict__ out4,
        int nA, int T) {
    __shared__ float red[256];
    __shared__ float sst[8];
    const int tid = threadIdx.x;
    {   // components: 0 pn,1 en,2 ps,3 pc (sums); 4..7 squares
        const int c = tid & 7;
        float v = 0.f;
        for (int i = tid >> 3; i < nA; i += 32) v += pA[i * 8 + c];
        red[tid] = v;
        __syncthreads();
        for (int off = 128; off >= 8; off >>= 1) {
            if (tid < off) red[tid] += red[tid + off];
            __syncthreads();
        }
        if (tid == 0) {
            const float invT = 1.0f / (float)T;
            #pragma unroll
            for (int k = 0; k < 4; ++k) {
                float mu  = red[k] * invT;
                float var = fmaxf(fmaf(-mu, mu, red[4 + k] * invT), 0.0f);
                sst[k]     = mu;
                sst[4 + k] = (var > 0.0f) ? rsqrtf(var) : 0.0f;
            }
        }
        __syncthreads();
    }
    const float mu0 = sst[0], mu1 = sst[1], mu2 = sst[2], mu3 = sst[3];
    const float is0 = sst[4], is1 = sst[5], is2 = sst[6], is3 = sst[7];
    for (int i = blockIdx.x * 256 + tid; i < T; i += 1024 * 256) {
        f32x4 v = out4[i];
        out4[i] = (f32x4){(v.x - mu0) * is0, (v.y - mu1) * is1,
                          (v.z - mu2) * is2, (v.w - mu3) * is3};
    }
}

// ---------------- round-1 fallback (proven; own WARMUP=2048, s0=0) ----------
#define L_CHUNK  128
#define FB_WARMUP 2048
__device__ __forceinline__ float inv1p_fb(float a) {
    float i1 = 1.0f - a;
    float i2 = fmaf(-a, i1, 1.0f);
    return fmaf(-a, i2, 1.0f);
}
struct SCfb { float x1, inv_x1, c49; };
__device__ __forceinline__ void scan_step_fb(float& s, float P, float E, const SCfb c,
                                             float& pn, float& en, float& ps, float& pc) {
    float d = P - E;
    float pn_ = fmaxf(d, 0.0f), en_ = fmaxf(-d, 0.0f);
    float up = pn_ * c.inv_x1;
    float tp = up * fmaf(up * up, -(1.0f / 3.0f), 1.0f);
    float un = en_ * c.inv_x1;
    float tn = un * fmaf(un * un, -(1.0f / 3.0f), 1.0f);
    float r = s * c.inv_x1;
    float ps_ = (tp * c.x1) * fmaf(-r, r, 1.0f) * inv1p_fb(r * tp);
    float es_ = (s * (2.0f - r)) * tn * inv1p_fb((1.0f - r) * tn);
    float s1 = s + ps_ - es_;
    float z = s1 * c.c49, z2 = z * z, v = z2 * z2;
    float t = fmaf(v, fmaf(v, 0.15625f, -0.25f), 1.0f);
    float s2 = s1 * t;
    pn = pn_; en = en_; ps = ps_; pc = s1 - s2; s = s2;
}
__global__ __launch_bounds__(256) void scan_kernel_fb(
        const float* __restrict__ x, const float* __restrict__ x1ptr,
        float* __restrict__ out, float* __restrict__ s_store,
        float* __restrict__ partials, int T) {
    const int c = blockIdx.x * blockDim.x + threadIdx.x;
    const int nchunks = (T + L_CHUNK - 1) / L_CHUNK;
    SCfb cc; cc.x1 = x1ptr[0]; cc.inv_x1 = 1.0f / cc.x1; cc.c49 = (4.0f / 9.0f) * cc.inv_x1;
    float s1a[4] = {0.f, 0.f, 0.f, 0.f};
    float s2a[4] = {0.f, 0.f, 0.f, 0.f};
    if (c < nchunks) {
        const int g0 = c * L_CHUNK;
        const int g1 = min(g0 + L_CHUNK, T);
        const int w0 = max(g0 - FB_WARMUP, 0);
        float s = 0.0f; float pn, en, ps, pc;
        const float2* __restrict__ x2 = (const float2*)x;
        for (int t = w0; t < g0; ++t) { float2 xv = x2[t]; scan_step_fb(s, xv.x, xv.y, cc, pn, en, ps, pc); }
        float4* __restrict__ out4 = (float4*)out;
        for (int t = g0; t < g1; ++t) {
            float2 xv = x2[t];
            scan_step_fb(s, xv.x, xv.y, cc, pn, en, ps, pc);
            out4[t] = make_float4(pn, en, ps, pc);
            s_store[t] = s;
            s1a[0] += pn; s1a[1] += en; s1a[2] += ps; s1a[3] += pc;
            s2a[0] = fmaf(pn, pn, s2a[0]); s2a[1] = fmaf(en, en, s2a[1]);
            s2a[2] = fmaf(ps, ps, s2a[2]); s2a[3] = fmaf(pc, pc, s2a[3]);
        }
    }
    __shared__ float red[256];
    float vals[8] = {s1a[0], s1a[1], s1a[2], s1a[3], s2a[0], s2a[1], s2a[2], s2a[3]};
    for (int k = 0; k < 8; ++k) {
        red[threadIdx.x] = vals[k];
        __syncthreads();
        for (int off = 128; off > 0; off >>= 1) {
            if ((int)threadIdx.x < off) red[threadIdx.x] += red[threadIdx.x + off];
            __syncthreads();
        }
        if (threadIdx.x == 0) partials[blockIdx.x * 8 + k] = red[0];
        __syncthreads();
    }
}
__global__ __launch_bounds__(64) void finalize_fb(
        const float* __restrict__ partials, float* __restrict__ stats, int nblk, int T) {
    const int lane = threadIdx.x;
    float v[8] = {0.f, 0.f, 0.f, 0.f, 0.f, 0.f, 0.f, 0.f};
    for (int b = lane; b < nblk; b += 64)
        for (int k = 0; k < 8; ++k) v[k] += partials[b * 8 + k];
    #pragma unroll
    for (int k = 0; k < 8; ++k)
        for (int off = 32; off > 0; off >>= 1) v[k] += __shfl_down(v[k], off, 64);
    if (lane == 0) {
        const float invT = 1.0f / (float)T;
        for (int k = 0; k < 4; ++k) {
            float mu = v[k] * invT;
            float var = fmaxf(fmaf(-mu, mu, v[k + 4] * invT), 0.0f);
            stats[k] = mu;
            stats[4 + k] = (var > 0.0f) ? rsqrtf(var) : 0.0f;
        }
    }
}
__global__ __launch_bounds__(256) void normalize_fb(
        float* __restrict__ out, const float* __restrict__ stats, int T) {
    const int t = blockIdx.x * blockDim.x + threadIdx.x;
    if (t >= T) return;
    const float4 mu = *(const float4*)stats;
    const float4 is = *(const float4*)(stats + 4);
    float4* o4 = (float4*)out;
    float4 v = o4[t];
    v.x = (v.x - mu.x) * is.x; v.y = (v.y - mu.y) * is.y;
    v.z = (v.z - mu.z) * is.z; v.w = (v.w - mu.w) * is.w;
    o4[t] = v;
}
// -----------------------------------------------------------------------------

extern "C" void kernel_launch(void* const* d_in, const int* in_sizes, int n_in,
                              void* d_out, int out_size, void* d_ws, size_t ws_size,
                              hipStream_t stream) {
    const float* x  = (const float*)d_in[0];
    const float* x1 = (const float*)d_in[1];
    const int T = in_sizes[0] / 2;

    float* out     = (float*)d_out;                // (T,4)
    float* s_store = out + 4 * (size_t)T;          // (T,)

    const int nblk = T / BSTEPS;                   // scan blocks (fast path)

    float* pA = (float*)d_ws;                      // nblk*8 floats (<=4096)
    const size_t need = 8192 * sizeof(float);

    const bool fast = (T % BSTEPS == 0) && nblk >= 1 && nblk <= 512 &&
                      (ws_size >= need);

    if (fast) {
        scan_fused<<<nblk, TPB, 0, stream>>>(x, x1, (f32x4*)out,
                                             (f32x4*)s_store, pA);
        normalize_stats<<<1024, 256, 0, stream>>>(pA, (f32x4*)out, nblk, T);
    } else {
        float* stats    = (float*)d_ws;
        float* partials = stats + 8;
        const int nchunks = (T + L_CHUNK - 1) / L_CHUNK;
        const int nblkA = (nchunks + 255) / 256;
        scan_kernel_fb<<<nblkA, 256, 0, stream>>>(x, x1, out, s_store, partials, T);
        finalize_fb<<<1, 64, 0, stream>>>(partials, stats, nblkA, T);
        normalize_fb<<<(T + 255) / 256, 256, 0, stream>>>(out, stats, T);
    }
}